// Round 4
// baseline (551.268 us; speedup 1.0000x reference)
//
#include <hip/hip_runtime.h>
#include <math.h>

// Problem constants (fixed by reference)
#define NN   10000
#define EE   160000
#define GG   128
#define HIDK 25
#define KE   26      // 25 MLP features + 1 constant row for b2
#define DOUT 32
#define EPSBN 1e-5f

// ---------------- workspace layout (float offsets) ----------------
// zeroed region (one hipMemsetAsync, ~97 KB):
#define OFF_CUR   0          // NN ints (scatter cursors)
#define OFF_GSUM  10016      // G*32
#define OFF_GCNT  14112      // G
#define OFF_DEGC  14240      // NN ints (degree counts)
#define ZERO_FLOATS 24256
// non-zeroed:
#define OFF_MOP   24256      // 64*12 moment partials
#define OFF_W1F   25024      // 75 (padded 80)
#define OFF_B1F   25104      // 25 (padded 32)
#define OFF_ROW   25136      // NN+1 ints (CSR row starts, padded 10016)
#define OFF_SRC   35152      // E ints (CSR src per slot)
#define OFF_EID   195152     // E ints (CSR edge id per slot)
#define OFF_Z     355152     // N*26*32 = 8,320,000
#define OFF_X1    8675152    // N*32
#define OFF_X2    8995152    // N*32
#define TOTAL_FLOATS 9315152 // ~37.3 MB of d_ws

__device__ inline float wave_red(float v) {
    for (int off = 32; off; off >>= 1) v += __shfl_down(v, off);
    return v;
}

// ---- stage 1: per-block moment partials (atomic-free)
__global__ void k_moments(const float* __restrict__ ea, float* __restrict__ mop) {
    __shared__ float ls[4][9];
    float s[9];
#pragma unroll
    for (int j = 0; j < 9; j++) s[j] = 0.f;
    int t = threadIdx.x;
    for (int e = blockIdx.x * 256 + t; e < EE; e += 64 * 256) {
        float a0 = ea[3 * e], a1 = ea[3 * e + 1], a2 = ea[3 * e + 2];
        s[0] += a0; s[1] += a1; s[2] += a2;
        s[3] += a0 * a0; s[4] += a0 * a1; s[5] += a0 * a2;
        s[6] += a1 * a1; s[7] += a1 * a2; s[8] += a2 * a2;
    }
    int w = t >> 6, lane = t & 63;
#pragma unroll
    for (int j = 0; j < 9; j++) {
        float r = wave_red(s[j]);
        if (lane == 0) ls[w][j] = r;
    }
    __syncthreads();
    if (t < 9) {
        float r = ls[0][t] + ls[1][t] + ls[2][t] + ls[3][t];
        mop[blockIdx.x * 12 + t] = r;
    }
}

// ---- in-degree (dst) counts
__global__ void k_deg(const int* __restrict__ ei, int* __restrict__ degc) {
    int e = blockIdx.x * blockDim.x + threadIdx.x;
    if (e < EE) atomicAdd(degc + ei[EE + e], 1);
}

// ---- single-block exclusive scan of degc -> row_start[NN+1]
__global__ void k_scan(const int* __restrict__ degc, int* __restrict__ row_start) {
    __shared__ int p[256];
    int t = threadIdx.x;
    const int CHUNK = 40;                 // 250*40 == 10000 exactly
    int base = t * CHUNK;
    int sum = 0;
    if (t < 250) {
        for (int i = 0; i < CHUNK; i++) sum += degc[base + i];
    }
    p[t] = sum;
    __syncthreads();
    for (int off = 1; off < 256; off <<= 1) {
        int v = (t >= off) ? p[t - off] : 0;
        __syncthreads();
        p[t] += v;
        __syncthreads();
    }
    int excl = p[t] - sum;
    if (t < 250) {
        int run = excl;
        for (int i = 0; i < CHUNK; i++) {
            row_start[base + i] = run;
            run += degc[base + i];
        }
    }
    if (t == 0) row_start[NN] = EE;
}

// ---- scatter edges into CSR slots
__global__ void k_scatter(const int* __restrict__ ei, const int* __restrict__ row_start,
                          int* __restrict__ cur, int* __restrict__ csr_src,
                          int* __restrict__ csr_eid) {
    int e = blockIdx.x * blockDim.x + threadIdx.x;
    if (e >= EE) return;
    int d = ei[EE + e];
    int pos = atomicAdd(cur + d, 1);
    int idx = row_start[d] + pos;
    csr_src[idx] = ei[e];
    csr_eid[idx] = e;
}

// ---- fold BN (analytic stats from partials) into w1', b1'
__global__ void k_fold(const float* __restrict__ mop, const float* __restrict__ w1,
                       const float* __restrict__ b1, const float* __restrict__ g,
                       const float* __restrict__ be, float* __restrict__ w1f,
                       float* __restrict__ b1f) {
    __shared__ float mo[9];
    int j = threadIdx.x;
    if (j < 9) {
        float s = 0.f;
        for (int b = 0; b < 64; b++) s += mop[b * 12 + j];
        mo[j] = s;
    }
    __syncthreads();
    if (j >= HIDK) return;
    const float inv = 1.0f / (float)EE;
    float m0 = mo[0] * inv, m1 = mo[1] * inv, m2 = mo[2] * inv;
    float c00 = mo[3] * inv - m0 * m0, c01 = mo[4] * inv - m0 * m1, c02 = mo[5] * inv - m0 * m2;
    float c11 = mo[6] * inv - m1 * m1, c12 = mo[7] * inv - m1 * m2, c22 = mo[8] * inv - m2 * m2;
    float w0 = w1[j], wa = w1[25 + j], wb = w1[50 + j];
    float mean = m0 * w0 + m1 * wa + m2 * wb + b1[j];
    float var = w0 * w0 * c00 + wa * wa * c11 + wb * wb * c22
              + 2.f * (w0 * wa * c01 + w0 * wb * c02 + wa * wb * c12);
    float sc = g[j] * rsqrtf(var + EPSBN);
    w1f[j] = w0 * sc; w1f[25 + j] = wa * sc; w1f[50 + j] = wb * sc;
    b1f[j] = (b1[j] - mean) * sc + be[j];
}

// ---- per-node z[n,k,o] = sum_i x[n,i]*w2[k,i,o]; row 25 = x@b2
// R3 rebuild: TILE_N=8 (1250 blocks), ds_read_b128 x-tile reads, acc[2] chunks
// to keep VGPR footprint ~50 (no spill). Thread = (o = t&31, kq = t>>5).
template <int DIN>
__global__ void k_z(const float* __restrict__ x, const float* __restrict__ w2,
                    const float* __restrict__ b2, float* __restrict__ z) {
    __shared__ __align__(16) float xs[8][DIN];
    int t = threadIdx.x;
    int n0 = blockIdx.x * 8;
    const int NV4 = 8 * DIN / 4;          // 32 (din16) or 64 (din32) float4s
    if (t < NV4) {
        ((float4*)&xs[0][0])[t] = ((const float4*)(x + n0 * DIN))[t];
    }
    __syncthreads();
    int o = t & 31, kq = t >> 5;
    for (int k = kq; k < KE; k += 8) {
        float w[DIN];
        const float* wp = (k < HIDK) ? (w2 + (size_t)k * DIN * DOUT + o) : (b2 + o);
#pragma unroll
        for (int i = 0; i < DIN; i++) w[i] = wp[i * DOUT];
        float* zp = z + (size_t)n0 * (KE * DOUT) + k * DOUT + o;
#pragma unroll
        for (int nc = 0; nc < 8; nc += 2) {
            float acc0 = 0.f, acc1 = 0.f;
#pragma unroll
            for (int i4 = 0; i4 < DIN / 4; i4++) {
                float4 a = ((const float4*)xs[nc + 0])[i4];
                float4 b = ((const float4*)xs[nc + 1])[i4];
                acc0 += a.x * w[4 * i4] + a.y * w[4 * i4 + 1] + a.z * w[4 * i4 + 2] + a.w * w[4 * i4 + 3];
                acc1 += b.x * w[4 * i4] + b.y * w[4 * i4 + 1] + b.z * w[4 * i4 + 2] + b.w * w[4 * i4 + 3];
            }
            zp[(nc + 0) * (KE * DOUT)] = acc0;
            zp[(nc + 1) * (KE * DOUT)] = acc1;
        }
    }
}

// ---- fused CSR edge-gather + scatter-mean + root transform + ELU (no atomics)
// One wave per dst node: 64 lanes = 2 edge slots x 32 o-lanes.
template <int DIN>
__global__ void k_edgenode(const float* __restrict__ ea, const int* __restrict__ row_start,
                           const int* __restrict__ csr_src, const int* __restrict__ csr_eid,
                           const float* __restrict__ w1f, const float* __restrict__ b1f,
                           const float* __restrict__ z, const float* __restrict__ xin,
                           const float* __restrict__ wr, const float* __restrict__ bc,
                           float* __restrict__ xout) {
    int t = threadIdx.x;
    int wid = t >> 6;             // 4 waves/block
    int lane = t & 63;
    int j = lane >> 5, o = lane & 31;
    int n = blockIdx.x * 4 + wid; // grid 2500 -> n in [0,10000)
    int start = row_start[n];
    int cnt = row_start[n + 1] - start;
    float acc = 0.f;
    for (int p = j; p < cnt; p += 2) {
        int ce = csr_eid[start + p];   // broadcast load (same addr per half-wave)
        int cs = csr_src[start + p];
        float hv = 0.f;
        if (o < HIDK) {
            float a0 = ea[3 * ce], a1 = ea[3 * ce + 1], a2 = ea[3 * ce + 2];
            float v = a0 * w1f[o] + a1 * w1f[25 + o] + a2 * w1f[50 + o] + b1f[o];
            hv = v > 0.f ? v : 0.f;
        } else if (o == HIDK) {
            hv = 1.0f;                 // constant row folding b2
        }
        const float* zp = z + (size_t)cs * (KE * DOUT) + o;
        float a = 0.f;
#pragma unroll
        for (int k = 0; k < KE; k++) a += __shfl(hv, (j << 5) + k) * zp[k * DOUT];
        acc += a;
    }
    acc += __shfl_xor(acc, 32);        // combine the two edge slots
    if (j == 0) {
        float d = (float)cnt; if (d < 1.f) d = 1.f;
        float r = acc / d + bc[o];
#pragma unroll
        for (int i = 0; i < DIN; i++) r += xin[n * DIN + i] * wr[i * DOUT + o];
        r = r > 0.f ? r : expm1f(r);
        xout[n * DOUT + o] = r;
    }
}

// ---- global mean pool accumulation
__global__ void k_pool(const float* __restrict__ x, const int* __restrict__ batch,
                       float* __restrict__ gsum, float* __restrict__ gcnt) {
    int idx = blockIdx.x * blockDim.x + threadIdx.x;
    if (idx >= NN * DOUT) return;
    int n = idx >> 5, o = idx & 31;
    int b = batch[n];
    atomicAdd(gsum + b * DOUT + o, x[idx]);
    if (o == 0) atomicAdd(gcnt + b, 1.0f);
}

// ---- final fc
__global__ void k_fc(const float* __restrict__ gsum, const float* __restrict__ gcnt,
                     const float* __restrict__ wfc, const float* __restrict__ bfc,
                     float* __restrict__ out) {
    int g = threadIdx.x;
    if (g >= GG) return;
    float c = gcnt[g]; c = c < 1.f ? 1.f : c;
    float acc = 0.f;
#pragma unroll
    for (int o = 0; o < DOUT; o++) acc += gsum[g * DOUT + o] * wfc[o];
    out[g] = acc / c + bfc[0];
}

extern "C" void kernel_launch(void* const* d_in, const int* in_sizes, int n_in,
                              void* d_out, int out_size, void* d_ws, size_t ws_size,
                              hipStream_t stream) {
    const float* x     = (const float*)d_in[0];
    const float* ea    = (const float*)d_in[1];
    const int*   ei    = (const int*)d_in[2];
    const int*   batch = (const int*)d_in[3];
    const float* w1_0 = (const float*)d_in[4];
    const float* b1_0 = (const float*)d_in[5];
    const float* g_0  = (const float*)d_in[6];
    const float* be_0 = (const float*)d_in[7];
    const float* w2_0 = (const float*)d_in[8];
    const float* b2_0 = (const float*)d_in[9];
    const float* wr_0 = (const float*)d_in[10];
    const float* bc_0 = (const float*)d_in[11];
    const float* w1_1 = (const float*)d_in[12];
    const float* b1_1 = (const float*)d_in[13];
    const float* g_1  = (const float*)d_in[14];
    const float* be_1 = (const float*)d_in[15];
    const float* w2_1 = (const float*)d_in[16];
    const float* b2_1 = (const float*)d_in[17];
    const float* wr_1 = (const float*)d_in[18];
    const float* bc_1 = (const float*)d_in[19];
    const float* wfc  = (const float*)d_in[20];
    const float* bfc  = (const float*)d_in[21];

    float* ws    = (float*)d_ws;
    int*   cur   = (int*)(ws + OFF_CUR);
    float* gsum  = ws + OFF_GSUM;
    float* gcnt  = ws + OFF_GCNT;
    int*   degc  = (int*)(ws + OFF_DEGC);
    float* mop   = ws + OFF_MOP;
    float* w1f   = ws + OFF_W1F;
    float* b1f   = ws + OFF_B1F;
    int*   row   = (int*)(ws + OFF_ROW);
    int*   csrc  = (int*)(ws + OFF_SRC);
    int*   ceid  = (int*)(ws + OFF_EID);
    float* z     = ws + OFF_Z;
    float* x1    = ws + OFF_X1;
    float* x2    = ws + OFF_X2;

    hipMemsetAsync(ws, 0, (size_t)ZERO_FLOATS * sizeof(float), stream);

    k_moments<<<64, 256, 0, stream>>>(ea, mop);
    k_deg<<<(EE + 255) / 256, 256, 0, stream>>>(ei, degc);
    k_scan<<<1, 256, 0, stream>>>(degc, row);
    k_scatter<<<(EE + 255) / 256, 256, 0, stream>>>(ei, row, cur, csrc, ceid);

    // ---- layer 0 (din=16)
    k_fold<<<1, 64, 0, stream>>>(mop, w1_0, b1_0, g_0, be_0, w1f, b1f);
    k_z<16><<<NN / 8, 256, 0, stream>>>(x, w2_0, b2_0, z);
    k_edgenode<16><<<NN / 4, 256, 0, stream>>>(ea, row, csrc, ceid, w1f, b1f, z, x, wr_0, bc_0, x1);

    // ---- layer 1 (din=32)
    k_fold<<<1, 64, 0, stream>>>(mop, w1_1, b1_1, g_1, be_1, w1f, b1f);
    k_z<32><<<NN / 8, 256, 0, stream>>>(x1, w2_1, b2_1, z);
    k_edgenode<32><<<NN / 4, 256, 0, stream>>>(ea, row, csrc, ceid, w1f, b1f, z, x1, wr_1, bc_1, x2);

    // ---- pool + fc
    k_pool<<<(NN * DOUT + 255) / 256, 256, 0, stream>>>(x2, batch, gsum, gcnt);
    k_fc<<<1, 128, 0, stream>>>(gsum, gcnt, wfc, bfc, (float*)d_out);
}

// Round 5
// 528.789 us; speedup vs baseline: 1.0425x; 1.0425x over previous
//
#include <hip/hip_runtime.h>
#include <math.h>

// Problem constants (fixed by reference)
#define NN   10000
#define EE   160000
#define GG   128
#define HIDK 25
#define KE   26      // 25 MLP features + 1 constant row for b2
#define DOUT 32
#define EPSBN 1e-5f

// ---------------- workspace layout (float offsets) ----------------
// zeroed region (one hipMemsetAsync, ~97 KB):
#define OFF_CUR   0          // NN ints (scatter cursors)
#define OFF_GSUM  10016      // G*32
#define OFF_GCNT  14112      // G
#define OFF_DEGC  14240      // NN ints (degree counts)
#define ZERO_FLOATS 24256
// non-zeroed:
#define OFF_MOP   24256      // 64*12 moment partials
#define OFF_W1F   25024      // 75 (padded 80)
#define OFF_B1F   25104      // 25 (padded 32)
#define OFF_ROW   25136      // NN+1 ints (CSR row starts, padded 10016)
#define OFF_SRC   35152      // E ints (CSR src per slot)
#define OFF_EID   195152     // E ints (CSR edge id per slot)
#define OFF_Z     355152     // N*26*32 = 8,320,000
#define OFF_X1    8675152    // N*32
#define OFF_X2    8995152    // N*32
#define TOTAL_FLOATS 9315152 // ~37.3 MB of d_ws

__device__ inline float wave_red(float v) {
    for (int off = 32; off; off >>= 1) v += __shfl_down(v, off);
    return v;
}

// ---- stage 1: per-block moment partials (atomic-free)
__global__ void k_moments(const float* __restrict__ ea, float* __restrict__ mop) {
    __shared__ float ls[4][9];
    float s[9];
#pragma unroll
    for (int j = 0; j < 9; j++) s[j] = 0.f;
    int t = threadIdx.x;
    for (int e = blockIdx.x * 256 + t; e < EE; e += 64 * 256) {
        float a0 = ea[3 * e], a1 = ea[3 * e + 1], a2 = ea[3 * e + 2];
        s[0] += a0; s[1] += a1; s[2] += a2;
        s[3] += a0 * a0; s[4] += a0 * a1; s[5] += a0 * a2;
        s[6] += a1 * a1; s[7] += a1 * a2; s[8] += a2 * a2;
    }
    int w = t >> 6, lane = t & 63;
#pragma unroll
    for (int j = 0; j < 9; j++) {
        float r = wave_red(s[j]);
        if (lane == 0) ls[w][j] = r;
    }
    __syncthreads();
    if (t < 9) {
        float r = ls[0][t] + ls[1][t] + ls[2][t] + ls[3][t];
        mop[blockIdx.x * 12 + t] = r;
    }
}

// ---- in-degree (dst) counts
__global__ void k_deg(const int* __restrict__ ei, int* __restrict__ degc) {
    int e = blockIdx.x * blockDim.x + threadIdx.x;
    if (e < EE) atomicAdd(degc + ei[EE + e], 1);
}

// ---- single-block exclusive scan of degc -> row_start[NN+1]
__global__ void k_scan(const int* __restrict__ degc, int* __restrict__ row_start) {
    __shared__ int p[256];
    int t = threadIdx.x;
    const int CHUNK = 40;                 // 250*40 == 10000 exactly
    int base = t * CHUNK;
    int sum = 0;
    if (t < 250) {
        for (int i = 0; i < CHUNK; i++) sum += degc[base + i];
    }
    p[t] = sum;
    __syncthreads();
    for (int off = 1; off < 256; off <<= 1) {
        int v = (t >= off) ? p[t - off] : 0;
        __syncthreads();
        p[t] += v;
        __syncthreads();
    }
    int excl = p[t] - sum;
    if (t < 250) {
        int run = excl;
        for (int i = 0; i < CHUNK; i++) {
            row_start[base + i] = run;
            run += degc[base + i];
        }
    }
    if (t == 0) row_start[NN] = EE;
}

// ---- scatter edges into CSR slots
__global__ void k_scatter(const int* __restrict__ ei, const int* __restrict__ row_start,
                          int* __restrict__ cur, int* __restrict__ csr_src,
                          int* __restrict__ csr_eid) {
    int e = blockIdx.x * blockDim.x + threadIdx.x;
    if (e >= EE) return;
    int d = ei[EE + e];
    int pos = atomicAdd(cur + d, 1);
    int idx = row_start[d] + pos;
    csr_src[idx] = ei[e];
    csr_eid[idx] = e;
}

// ---- fold BN (analytic stats from partials) into w1', b1'
__global__ void k_fold(const float* __restrict__ mop, const float* __restrict__ w1,
                       const float* __restrict__ b1, const float* __restrict__ g,
                       const float* __restrict__ be, float* __restrict__ w1f,
                       float* __restrict__ b1f) {
    __shared__ float mo[9];
    int j = threadIdx.x;
    if (j < 9) {
        float s = 0.f;
        for (int b = 0; b < 64; b++) s += mop[b * 12 + j];
        mo[j] = s;
    }
    __syncthreads();
    if (j >= HIDK) return;
    const float inv = 1.0f / (float)EE;
    float m0 = mo[0] * inv, m1 = mo[1] * inv, m2 = mo[2] * inv;
    float c00 = mo[3] * inv - m0 * m0, c01 = mo[4] * inv - m0 * m1, c02 = mo[5] * inv - m0 * m2;
    float c11 = mo[6] * inv - m1 * m1, c12 = mo[7] * inv - m1 * m2, c22 = mo[8] * inv - m2 * m2;
    float w0 = w1[j], wa = w1[25 + j], wb = w1[50 + j];
    float mean = m0 * w0 + m1 * wa + m2 * wb + b1[j];
    float var = w0 * w0 * c00 + wa * wa * c11 + wb * wb * c22
              + 2.f * (w0 * wa * c01 + w0 * wb * c02 + wa * wb * c12);
    float sc = g[j] * rsqrtf(var + EPSBN);
    w1f[j] = w0 * sc; w1f[25 + j] = wa * sc; w1f[50 + j] = wb * sc;
    b1f[j] = (b1[j] - mean) * sc + be[j];
}

// ---- per-node z[n,k,o] = sum_i x[n,i]*w2[k,i,o]; row 25 = x@b2
// R4: NO per-thread indexed arrays spanning DIN (R2/R3 spilled w[DIN] to
// scratch -> 100s of MB of HBM traffic). i-loop chunked into 8 scalar w regs,
// acc[8] fully unrolled. ~40 live VGPRs. launch_bounds raises alloc ceiling.
template <int DIN>
__launch_bounds__(256, 4)
__global__ void k_z(const float* __restrict__ x, const float* __restrict__ w2,
                    const float* __restrict__ b2, float* __restrict__ z) {
    __shared__ __align__(16) float xs[8][DIN];
    int t = threadIdx.x;
    int n0 = blockIdx.x * 8;
    const int NV4 = 8 * DIN / 4;          // 32 (din16) or 64 (din32) float4s
    if (t < NV4) {
        ((float4*)&xs[0][0])[t] = ((const float4*)(x + n0 * DIN))[t];
    }
    __syncthreads();
    int o = t & 31, kq = t >> 5;
    for (int k = kq; k < KE; k += 8) {
        const float* wp = (k < HIDK) ? (w2 + (size_t)k * DIN * DOUT + o) : (b2 + o);
        float acc0 = 0.f, acc1 = 0.f, acc2 = 0.f, acc3 = 0.f;
        float acc4 = 0.f, acc5 = 0.f, acc6 = 0.f, acc7 = 0.f;
#pragma unroll
        for (int c = 0; c < DIN; c += 8) {
            float w0 = wp[(c + 0) * DOUT], w1v = wp[(c + 1) * DOUT];
            float w2v = wp[(c + 2) * DOUT], w3 = wp[(c + 3) * DOUT];
            float w4 = wp[(c + 4) * DOUT], w5 = wp[(c + 5) * DOUT];
            float w6 = wp[(c + 6) * DOUT], w7 = wp[(c + 7) * DOUT];
#pragma unroll
            for (int n = 0; n < 8; n++) {
                float4 a = *((const float4*)&xs[n][c]);
                float4 b = *((const float4*)&xs[n][c + 4]);
                float pa = a.x * w0 + a.y * w1v + a.z * w2v + a.w * w3
                         + b.x * w4 + b.y * w5 + b.z * w6 + b.w * w7;
                switch (n) {
                    case 0: acc0 += pa; break; case 1: acc1 += pa; break;
                    case 2: acc2 += pa; break; case 3: acc3 += pa; break;
                    case 4: acc4 += pa; break; case 5: acc5 += pa; break;
                    case 6: acc6 += pa; break; case 7: acc7 += pa; break;
                }
            }
        }
        float* zp = z + (size_t)n0 * (KE * DOUT) + k * DOUT + o;
        zp[0 * (KE * DOUT)] = acc0; zp[1 * (KE * DOUT)] = acc1;
        zp[2 * (KE * DOUT)] = acc2; zp[3 * (KE * DOUT)] = acc3;
        zp[4 * (KE * DOUT)] = acc4; zp[5 * (KE * DOUT)] = acc5;
        zp[6 * (KE * DOUT)] = acc6; zp[7 * (KE * DOUT)] = acc7;
    }
}

// ---- fused CSR edge-gather + scatter-mean + root transform + ELU (no atomics)
// One wave per dst node: 64 lanes = 2 edge slots x 32 o-lanes.
template <int DIN>
__global__ void k_edgenode(const float* __restrict__ ea, const int* __restrict__ row_start,
                           const int* __restrict__ csr_src, const int* __restrict__ csr_eid,
                           const float* __restrict__ w1f, const float* __restrict__ b1f,
                           const float* __restrict__ z, const float* __restrict__ xin,
                           const float* __restrict__ wr, const float* __restrict__ bc,
                           float* __restrict__ xout) {
    int t = threadIdx.x;
    int wid = t >> 6;             // 4 waves/block
    int lane = t & 63;
    int j = lane >> 5, o = lane & 31;
    int n = blockIdx.x * 4 + wid; // grid 2500 -> n in [0,10000)
    int start = row_start[n];
    int cnt = row_start[n + 1] - start;
    float acc = 0.f;
    for (int p = j; p < cnt; p += 2) {
        int ce = csr_eid[start + p];   // broadcast load (same addr per half-wave)
        int cs = csr_src[start + p];
        float hv = 0.f;
        if (o < HIDK) {
            float a0 = ea[3 * ce], a1 = ea[3 * ce + 1], a2 = ea[3 * ce + 2];
            float v = a0 * w1f[o] + a1 * w1f[25 + o] + a2 * w1f[50 + o] + b1f[o];
            hv = v > 0.f ? v : 0.f;
        } else if (o == HIDK) {
            hv = 1.0f;                 // constant row folding b2
        }
        const float* zp = z + (size_t)cs * (KE * DOUT) + o;
        float a = 0.f;
#pragma unroll
        for (int k = 0; k < KE; k++) a += __shfl(hv, (j << 5) + k) * zp[k * DOUT];
        acc += a;
    }
    acc += __shfl_xor(acc, 32);        // combine the two edge slots
    if (j == 0) {
        float d = (float)cnt; if (d < 1.f) d = 1.f;
        float r = acc / d + bc[o];
#pragma unroll
        for (int i = 0; i < DIN; i++) r += xin[n * DIN + i] * wr[i * DOUT + o];
        r = r > 0.f ? r : expm1f(r);
        xout[n * DOUT + o] = r;
    }
}

// ---- global mean pool accumulation
__global__ void k_pool(const float* __restrict__ x, const int* __restrict__ batch,
                       float* __restrict__ gsum, float* __restrict__ gcnt) {
    int idx = blockIdx.x * blockDim.x + threadIdx.x;
    if (idx >= NN * DOUT) return;
    int n = idx >> 5, o = idx & 31;
    int b = batch[n];
    atomicAdd(gsum + b * DOUT + o, x[idx]);
    if (o == 0) atomicAdd(gcnt + b, 1.0f);
}

// ---- final fc
__global__ void k_fc(const float* __restrict__ gsum, const float* __restrict__ gcnt,
                     const float* __restrict__ wfc, const float* __restrict__ bfc,
                     float* __restrict__ out) {
    int g = threadIdx.x;
    if (g >= GG) return;
    float c = gcnt[g]; c = c < 1.f ? 1.f : c;
    float acc = 0.f;
#pragma unroll
    for (int o = 0; o < DOUT; o++) acc += gsum[g * DOUT + o] * wfc[o];
    out[g] = acc / c + bfc[0];
}

extern "C" void kernel_launch(void* const* d_in, const int* in_sizes, int n_in,
                              void* d_out, int out_size, void* d_ws, size_t ws_size,
                              hipStream_t stream) {
    const float* x     = (const float*)d_in[0];
    const float* ea    = (const float*)d_in[1];
    const int*   ei    = (const int*)d_in[2];
    const int*   batch = (const int*)d_in[3];
    const float* w1_0 = (const float*)d_in[4];
    const float* b1_0 = (const float*)d_in[5];
    const float* g_0  = (const float*)d_in[6];
    const float* be_0 = (const float*)d_in[7];
    const float* w2_0 = (const float*)d_in[8];
    const float* b2_0 = (const float*)d_in[9];
    const float* wr_0 = (const float*)d_in[10];
    const float* bc_0 = (const float*)d_in[11];
    const float* w1_1 = (const float*)d_in[12];
    const float* b1_1 = (const float*)d_in[13];
    const float* g_1  = (const float*)d_in[14];
    const float* be_1 = (const float*)d_in[15];
    const float* w2_1 = (const float*)d_in[16];
    const float* b2_1 = (const float*)d_in[17];
    const float* wr_1 = (const float*)d_in[18];
    const float* bc_1 = (const float*)d_in[19];
    const float* wfc  = (const float*)d_in[20];
    const float* bfc  = (const float*)d_in[21];

    float* ws    = (float*)d_ws;
    int*   cur   = (int*)(ws + OFF_CUR);
    float* gsum  = ws + OFF_GSUM;
    float* gcnt  = ws + OFF_GCNT;
    int*   degc  = (int*)(ws + OFF_DEGC);
    float* mop   = ws + OFF_MOP;
    float* w1f   = ws + OFF_W1F;
    float* b1f   = ws + OFF_B1F;
    int*   row   = (int*)(ws + OFF_ROW);
    int*   csrc  = (int*)(ws + OFF_SRC);
    int*   ceid  = (int*)(ws + OFF_EID);
    float* z     = ws + OFF_Z;
    float* x1    = ws + OFF_X1;
    float* x2    = ws + OFF_X2;

    hipMemsetAsync(ws, 0, (size_t)ZERO_FLOATS * sizeof(float), stream);

    k_moments<<<64, 256, 0, stream>>>(ea, mop);
    k_deg<<<(EE + 255) / 256, 256, 0, stream>>>(ei, degc);
    k_scan<<<1, 256, 0, stream>>>(degc, row);
    k_scatter<<<(EE + 255) / 256, 256, 0, stream>>>(ei, row, cur, csrc, ceid);

    // ---- layer 0 (din=16)
    k_fold<<<1, 64, 0, stream>>>(mop, w1_0, b1_0, g_0, be_0, w1f, b1f);
    k_z<16><<<NN / 8, 256, 0, stream>>>(x, w2_0, b2_0, z);
    k_edgenode<16><<<NN / 4, 256, 0, stream>>>(ea, row, csrc, ceid, w1f, b1f, z, x, wr_0, bc_0, x1);

    // ---- layer 1 (din=32)
    k_fold<<<1, 64, 0, stream>>>(mop, w1_1, b1_1, g_1, be_1, w1f, b1f);
    k_z<32><<<NN / 8, 256, 0, stream>>>(x1, w2_1, b2_1, z);
    k_edgenode<32><<<NN / 4, 256, 0, stream>>>(ea, row, csrc, ceid, w1f, b1f, z, x1, wr_1, bc_1, x2);

    // ---- pool + fc
    k_pool<<<(NN * DOUT + 255) / 256, 256, 0, stream>>>(x2, batch, gsum, gcnt);
    k_fc<<<1, 128, 0, stream>>>(gsum, gcnt, wfc, bfc, (float*)d_out);
}

// Round 6
// 308.359 us; speedup vs baseline: 1.7877x; 1.7148x over previous
//
#include <hip/hip_runtime.h>
#include <math.h>

// Problem constants (fixed by reference)
#define NN   10000
#define EE   160000
#define GG   128
#define HIDK 25
#define KROWS 28     // 25 MLP rows + 1 b2 row (k=25) + 2 zero-pad rows
#define DOUT 32
#define EPSBN 1e-5f

// ---------------- workspace layout (float offsets) ----------------
// zeroed region (one hipMemsetAsync, ~97 KB):
#define OFF_CUR   0          // NN ints (scatter cursors)
#define OFF_GSUM  10016      // G*32
#define OFF_GCNT  14112      // G
#define OFF_DEGC  14240      // NN ints (degree counts)
#define ZERO_FLOATS 24256
// non-zeroed:
#define OFF_MOP   24256      // 64*12 moment partials
#define OFF_W1F   25024      // 75 (padded 80)
#define OFF_B1F   25104      // 25 (padded 32)
#define OFF_ROW   25136      // NN+1 ints (CSR row starts, padded 10016)
#define OFF_SRC   35152      // E ints (CSR src per slot)
#define OFF_EID   195152     // E ints (CSR edge id per slot)
#define OFF_WB0   355152     // 28*16*32 = 14336  (w2_0 || b2_0 || zeros)
#define OFF_WB1   369488     // 28*32*32 = 28672  (w2_1 || b2_1 || zeros)
#define OFF_X1    398160     // N*32
#define OFF_X2    718160     // N*32
#define TOTAL_FLOATS 1038160 // ~4.2 MB of d_ws

__device__ inline float wave_red(float v) {
    for (int off = 32; off; off >>= 1) v += __shfl_down(v, off);
    return v;
}

// ---- stage 1: per-block moment partials (atomic-free)
__global__ void k_moments(const float* __restrict__ ea, float* __restrict__ mop) {
    __shared__ float ls[4][9];
    float s[9];
#pragma unroll
    for (int j = 0; j < 9; j++) s[j] = 0.f;
    int t = threadIdx.x;
    for (int e = blockIdx.x * 256 + t; e < EE; e += 64 * 256) {
        float a0 = ea[3 * e], a1 = ea[3 * e + 1], a2 = ea[3 * e + 2];
        s[0] += a0; s[1] += a1; s[2] += a2;
        s[3] += a0 * a0; s[4] += a0 * a1; s[5] += a0 * a2;
        s[6] += a1 * a1; s[7] += a1 * a2; s[8] += a2 * a2;
    }
    int w = t >> 6, lane = t & 63;
#pragma unroll
    for (int j = 0; j < 9; j++) {
        float r = wave_red(s[j]);
        if (lane == 0) ls[w][j] = r;
    }
    __syncthreads();
    if (t < 9) {
        float r = ls[0][t] + ls[1][t] + ls[2][t] + ls[3][t];
        mop[blockIdx.x * 12 + t] = r;
    }
}

// ---- in-degree (dst) counts
__global__ void k_deg(const int* __restrict__ ei, int* __restrict__ degc) {
    int e = blockIdx.x * blockDim.x + threadIdx.x;
    if (e < EE) atomicAdd(degc + ei[EE + e], 1);
}

// ---- single-block exclusive scan of degc -> row_start[NN+1]
__global__ void k_scan(const int* __restrict__ degc, int* __restrict__ row_start) {
    __shared__ int p[256];
    int t = threadIdx.x;
    const int CHUNK = 40;                 // 250*40 == 10000 exactly
    int base = t * CHUNK;
    int sum = 0;
    if (t < 250) {
        for (int i = 0; i < CHUNK; i++) sum += degc[base + i];
    }
    p[t] = sum;
    __syncthreads();
    for (int off = 1; off < 256; off <<= 1) {
        int v = (t >= off) ? p[t - off] : 0;
        __syncthreads();
        p[t] += v;
        __syncthreads();
    }
    int excl = p[t] - sum;
    if (t < 250) {
        int run = excl;
        for (int i = 0; i < CHUNK; i++) {
            row_start[base + i] = run;
            run += degc[base + i];
        }
    }
    if (t == 0) row_start[NN] = EE;
}

// ---- scatter edges into CSR slots
__global__ void k_scatter(const int* __restrict__ ei, const int* __restrict__ row_start,
                          int* __restrict__ cur, int* __restrict__ csr_src,
                          int* __restrict__ csr_eid) {
    int e = blockIdx.x * blockDim.x + threadIdx.x;
    if (e >= EE) return;
    int d = ei[EE + e];
    int pos = atomicAdd(cur + d, 1);
    int idx = row_start[d] + pos;
    csr_src[idx] = ei[e];
    csr_eid[idx] = e;
}

// ---- fold BN (analytic stats from partials) into w1', b1'
__global__ void k_fold(const float* __restrict__ mop, const float* __restrict__ w1,
                       const float* __restrict__ b1, const float* __restrict__ g,
                       const float* __restrict__ be, float* __restrict__ w1f,
                       float* __restrict__ b1f) {
    __shared__ float mo[9];
    int j = threadIdx.x;
    if (j < 9) {
        float s = 0.f;
        for (int b = 0; b < 64; b++) s += mop[b * 12 + j];
        mo[j] = s;
    }
    __syncthreads();
    if (j >= HIDK) return;
    const float inv = 1.0f / (float)EE;
    float m0 = mo[0] * inv, m1 = mo[1] * inv, m2 = mo[2] * inv;
    float c00 = mo[3] * inv - m0 * m0, c01 = mo[4] * inv - m0 * m1, c02 = mo[5] * inv - m0 * m2;
    float c11 = mo[6] * inv - m1 * m1, c12 = mo[7] * inv - m1 * m2, c22 = mo[8] * inv - m2 * m2;
    float w0 = w1[j], wa = w1[25 + j], wb = w1[50 + j];
    float mean = m0 * w0 + m1 * wa + m2 * wb + b1[j];
    float var = w0 * w0 * c00 + wa * wa * c11 + wb * wb * c22
              + 2.f * (w0 * wa * c01 + w0 * wb * c02 + wa * wb * c12);
    float sc = g[j] * rsqrtf(var + EPSBN);
    w1f[j] = w0 * sc; w1f[25 + j] = wa * sc; w1f[50 + j] = wb * sc;
    b1f[j] = (b1[j] - mean) * sc + be[j];
}

// ---- pack wbig[k][i][o]: rows 0..24 = w2, row 25 = b2, rows 26..27 = 0
template <int DIN>
__global__ void k_wprep(const float* __restrict__ w2, const float* __restrict__ b2,
                        float* __restrict__ wbig) {
    int idx = blockIdx.x * 256 + threadIdx.x;
    if (idx >= KROWS * DIN * DOUT) return;
    int k = idx / (DIN * DOUT);
    int r = idx - k * (DIN * DOUT);
    float v = 0.f;
    if (k < HIDK) v = w2[k * DIN * DOUT + r];
    else if (k == HIDK) v = b2[r];
    wbig[idx] = v;
}

// ---- FUSED layer kernel (replaces k_z + k_edgenode; z never materialized).
// One wave per dst node. Phase A: accumulate S[k][i] = sum_e h_ek * x[src_e,i]
// in registers (s[KPL], fully unrolled -> no scratch). Row k=25 uses h=1 (b2).
// Phase B: S -> LDS, out[o] = sum_{k,i} S[k,i]*wbig[k,i,o] + root + ELU.
// Lane layout A: i = lane & (DIN-1); kh = lane/DIN; owns k = kh*KPL + j.
// din32: KPL=14 (2 groups, k 0..27); din16: KPL=7 (4 groups, k 0..27).
template <int DIN, int KPL>
__global__ void k_fused(const float* __restrict__ ea, const int* __restrict__ row_start,
                        const int* __restrict__ csr_src, const int* __restrict__ csr_eid,
                        const float* __restrict__ w1f, const float* __restrict__ b1f,
                        const float* __restrict__ wbig, const float* __restrict__ xin,
                        const float* __restrict__ wr, const float* __restrict__ bc,
                        float* __restrict__ xout) {
    __shared__ __align__(16) float Slds[4][KROWS][DIN];
    int t = threadIdx.x;
    int w = t >> 6;
    int lane = t & 63;
    int n = blockIdx.x * 4 + w;            // grid 2500 -> n in [0,10000)
    int start = row_start[n];
    int cnt = row_start[n + 1] - start;

    // ---- Phase A ----
    int il = lane & (DIN - 1);
    int kh = lane / DIN;
    // hoisted folded-BN weights for this lane's h component
    float wa = 0.f, wb = 0.f, wc = 0.f, bb = 0.f;
    if (lane < HIDK) { wa = w1f[lane]; wb = w1f[25 + lane]; wc = w1f[50 + lane]; bb = b1f[lane]; }
    float s[KPL];
#pragma unroll
    for (int j = 0; j < KPL; j++) s[j] = 0.f;

    for (int p = 0; p < cnt; p++) {
        int e  = csr_eid[start + p];       // lane-uniform
        int sr = csr_src[start + p];
        float xv = xin[sr * DIN + il];     // 128B gather per edge
        float a0 = ea[3 * e], a1 = ea[3 * e + 1], a2 = ea[3 * e + 2];
        float hk;
        if (lane < HIDK) {
            float v = a0 * wa + a1 * wb + a2 * wc + bb;
            hk = v > 0.f ? v : 0.f;
        } else {
            hk = (lane == HIDK) ? 1.0f : 0.0f;   // b2 row; pad rows 0
        }
#pragma unroll
        for (int j = 0; j < KPL; j++)
            s[j] += __shfl(hk, kh * KPL + j) * xv;
    }
#pragma unroll
    for (int j = 0; j < KPL; j++)
        Slds[w][kh * KPL + j][il] = s[j];
    __syncthreads();

    // ---- Phase B ----
    int o = lane & 31, half = lane >> 5;   // halves split KROWS as 14+14
    float acc = 0.f;
    for (int kk = 0; kk < KROWS / 2; kk++) {
        int k = half * (KROWS / 2) + kk;
        const float* wrow = wbig + (size_t)k * DIN * DOUT + o;
#pragma unroll
        for (int i4 = 0; i4 < DIN / 4; i4++) {
            float4 sv = *(const float4*)&Slds[w][k][i4 * 4];
            acc += sv.x * wrow[(i4 * 4 + 0) * DOUT]
                 + sv.y * wrow[(i4 * 4 + 1) * DOUT]
                 + sv.z * wrow[(i4 * 4 + 2) * DOUT]
                 + sv.w * wrow[(i4 * 4 + 3) * DOUT];
        }
    }
    acc += __shfl_xor(acc, 32);            // combine halves
    if (half == 0) {
        float d = (float)cnt; if (d < 1.f) d = 1.f;
        float r = acc / d + bc[o];
#pragma unroll
        for (int i = 0; i < DIN; i++) r += xin[n * DIN + i] * wr[i * DOUT + o];
        r = r > 0.f ? r : expm1f(r);
        xout[n * DOUT + o] = r;
    }
}

// ---- global mean pool accumulation
__global__ void k_pool(const float* __restrict__ x, const int* __restrict__ batch,
                       float* __restrict__ gsum, float* __restrict__ gcnt) {
    int idx = blockIdx.x * blockDim.x + threadIdx.x;
    if (idx >= NN * DOUT) return;
    int n = idx >> 5, o = idx & 31;
    int b = batch[n];
    atomicAdd(gsum + b * DOUT + o, x[idx]);
    if (o == 0) atomicAdd(gcnt + b, 1.0f);
}

// ---- final fc
__global__ void k_fc(const float* __restrict__ gsum, const float* __restrict__ gcnt,
                     const float* __restrict__ wfc, const float* __restrict__ bfc,
                     float* __restrict__ out) {
    int g = threadIdx.x;
    if (g >= GG) return;
    float c = gcnt[g]; c = c < 1.f ? 1.f : c;
    float acc = 0.f;
#pragma unroll
    for (int o = 0; o < DOUT; o++) acc += gsum[g * DOUT + o] * wfc[o];
    out[g] = acc / c + bfc[0];
}

extern "C" void kernel_launch(void* const* d_in, const int* in_sizes, int n_in,
                              void* d_out, int out_size, void* d_ws, size_t ws_size,
                              hipStream_t stream) {
    const float* x     = (const float*)d_in[0];
    const float* ea    = (const float*)d_in[1];
    const int*   ei    = (const int*)d_in[2];
    const int*   batch = (const int*)d_in[3];
    const float* w1_0 = (const float*)d_in[4];
    const float* b1_0 = (const float*)d_in[5];
    const float* g_0  = (const float*)d_in[6];
    const float* be_0 = (const float*)d_in[7];
    const float* w2_0 = (const float*)d_in[8];
    const float* b2_0 = (const float*)d_in[9];
    const float* wr_0 = (const float*)d_in[10];
    const float* bc_0 = (const float*)d_in[11];
    const float* w1_1 = (const float*)d_in[12];
    const float* b1_1 = (const float*)d_in[13];
    const float* g_1  = (const float*)d_in[14];
    const float* be_1 = (const float*)d_in[15];
    const float* w2_1 = (const float*)d_in[16];
    const float* b2_1 = (const float*)d_in[17];
    const float* wr_1 = (const float*)d_in[18];
    const float* bc_1 = (const float*)d_in[19];
    const float* wfc  = (const float*)d_in[20];
    const float* bfc  = (const float*)d_in[21];

    float* ws    = (float*)d_ws;
    int*   cur   = (int*)(ws + OFF_CUR);
    float* gsum  = ws + OFF_GSUM;
    float* gcnt  = ws + OFF_GCNT;
    int*   degc  = (int*)(ws + OFF_DEGC);
    float* mop   = ws + OFF_MOP;
    float* w1f   = ws + OFF_W1F;
    float* b1f   = ws + OFF_B1F;
    int*   row   = (int*)(ws + OFF_ROW);
    int*   csrc  = (int*)(ws + OFF_SRC);
    int*   ceid  = (int*)(ws + OFF_EID);
    float* wb0   = ws + OFF_WB0;
    float* wb1   = ws + OFF_WB1;
    float* x1    = ws + OFF_X1;
    float* x2    = ws + OFF_X2;

    hipMemsetAsync(ws, 0, (size_t)ZERO_FLOATS * sizeof(float), stream);

    k_moments<<<64, 256, 0, stream>>>(ea, mop);
    k_deg<<<(EE + 255) / 256, 256, 0, stream>>>(ei, degc);
    k_scan<<<1, 256, 0, stream>>>(degc, row);
    k_scatter<<<(EE + 255) / 256, 256, 0, stream>>>(ei, row, cur, csrc, ceid);
    k_wprep<16><<<(KROWS * 16 * DOUT + 255) / 256, 256, 0, stream>>>(w2_0, b2_0, wb0);
    k_wprep<32><<<(KROWS * 32 * DOUT + 255) / 256, 256, 0, stream>>>(w2_1, b2_1, wb1);

    // ---- layer 0 (din=16)
    k_fold<<<1, 64, 0, stream>>>(mop, w1_0, b1_0, g_0, be_0, w1f, b1f);
    k_fused<16, 7><<<NN / 4, 256, 0, stream>>>(ea, row, csrc, ceid, w1f, b1f, wb0, x, wr_0, bc_0, x1);

    // ---- layer 1 (din=32)
    k_fold<<<1, 64, 0, stream>>>(mop, w1_1, b1_1, g_1, be_1, w1f, b1f);
    k_fused<32, 14><<<NN / 4, 256, 0, stream>>>(ea, row, csrc, ceid, w1f, b1f, wb1, x1, wr_1, bc_1, x2);

    // ---- pool + fc
    k_pool<<<(NN * DOUT + 255) / 256, 256, 0, stream>>>(x2, batch, gsum, gcnt);
    k_fc<<<1, 128, 0, stream>>>(gsum, gcnt, wfc, bfc, (float*)d_out);
}